// Round 6
// baseline (135.259 us; speedup 1.0000x reference)
//
#include <hip/hip_runtime.h>

namespace {

constexpr int B = 4, L = 4096, HC = 4, D = 1024, K = 4, DIL = 2;
constexpr int PAD = (K - 1) * DIL;   // 6
constexpr float EPS = 1e-5f;
constexpr int CL = 64;               // rows per block
constexpr int ST = 8;                // rows per step
constexpr int NSTEP = CL / ST;       // 8
constexpr int NT = L / CL;           // 64
constexpr int BDIM = 256;            // 4 waves

typedef float f32x4 __attribute__((ext_vector_type(4)));

// Barrier that does NOT drain vmcnt: LDS ordering only. Register-destination
// global prefetch loads stay in flight across it.
#define BLOCK_BARRIER() do {                                   \
    asm volatile("s_waitcnt lgkmcnt(0)" ::: "memory");         \
    __builtin_amdgcn_s_barrier();                              \
    asm volatile("" ::: "memory");                             \
} while (0)

__global__ __launch_bounds__(BDIM, 4) void engram_shortconv_dbuf(
    const float* __restrict__ x,
    const float* __restrict__ nw,
    const float* __restrict__ cw,
    float* __restrict__ out)
{
    __shared__ float s_part[ST][BDIM];   // 8 KiB
    __shared__ float s_invS[ST];

    const int blk = blockIdx.x;
    const int t   = blk % NT;
    const int hc  = (blk / NT) % HC;
    const int b   = blk / (NT * HC);
    const int l0  = t * CL;

    const int tid  = threadIdx.x;
    const int wave = tid >> 6;
    const int lane = tid & 63;

    const size_t rs = (size_t)HC * D;
    const float* xcol = x   + ((size_t)b * L * HC + (size_t)hc) * D + tid * 4;
    float*       ocol = out + ((size_t)b * L * HC + (size_t)hc) * D + tid * 4;

    // ---- issue weight loads first (so folding waits only on these) ----
    const float4 nw4 = *(const float4*)(nw + (size_t)hc * D + tid * 4);
    float4 cwv[4];
    #pragma unroll
    for (int j = 0; j < 4; ++j)
        cwv[j] = *(const float4*)(cw + ((size_t)hc * D + tid * 4 + j) * K);

    // ---- issue halo + step0 + step1 loads ----
    float win[PAD][4];   // rows l0-6 .. l0-1 (raw, then scaled)
    float A[ST][4], Bv[ST][4];
    if (l0 >= PAD) {
        #pragma unroll
        for (int r = 0; r < PAD; ++r) {
            const float4 v = *(const float4*)(xcol + (size_t)(l0 - PAD + r) * rs);
            win[r][0] = v.x; win[r][1] = v.y; win[r][2] = v.z; win[r][3] = v.w;
        }
    } else {
        #pragma unroll
        for (int r = 0; r < PAD; ++r) {
            const int l = l0 - PAD + r;
            float4 v = make_float4(0.f, 0.f, 0.f, 0.f);
            if (l >= 0) v = *(const float4*)(xcol + (size_t)l * rs);
            win[r][0] = v.x; win[r][1] = v.y; win[r][2] = v.z; win[r][3] = v.w;
        }
    }
    #pragma unroll
    for (int r = 0; r < ST; ++r) {
        const float4 v = *(const float4*)(xcol + (size_t)(l0 + r) * rs);
        A[r][0] = v.x; A[r][1] = v.y; A[r][2] = v.z; A[r][3] = v.w;
    }
    #pragma unroll
    for (int r = 0; r < ST; ++r) {
        const float4 v = *(const float4*)(xcol + (size_t)(l0 + ST + r) * rs);
        Bv[r][0] = v.x; Bv[r][1] = v.y; Bv[r][2] = v.z; Bv[r][3] = v.w;
    }

    // ---- fold norm gain into conv taps (overlaps x loads) ----
    float wk[4][4];
    {
        const float gv[4] = { nw4.x, nw4.y, nw4.z, nw4.w };
        #pragma unroll
        for (int j = 0; j < 4; ++j) {
            wk[j][0] = cwv[j].x * gv[j]; wk[j][1] = cwv[j].y * gv[j];
            wk[j][2] = cwv[j].z * gv[j]; wk[j][3] = cwv[j].w * gv[j];
        }
    }

    // ---- prologue: halo RMS ----
    #pragma unroll
    for (int r = 0; r < PAD; ++r)
        s_part[r][tid] = win[r][0]*win[r][0] + win[r][1]*win[r][1]
                       + win[r][2]*win[r][2] + win[r][3]*win[r][3];
    BLOCK_BARRIER();
    {
        int rr = wave;
        float s = s_part[rr][lane]       + s_part[rr][lane + 64]
                + s_part[rr][lane + 128] + s_part[rr][lane + 192];
        #pragma unroll
        for (int off = 32; off >= 1; off >>= 1) s += __shfl_xor(s, off);
        if (lane == 0) s_invS[rr] = rsqrtf(s * (1.0f / D) + EPS);
        rr = wave + 4;
        if (rr < PAD) {
            float s2 = s_part[rr][lane]       + s_part[rr][lane + 64]
                     + s_part[rr][lane + 128] + s_part[rr][lane + 192];
            #pragma unroll
            for (int off = 32; off >= 1; off >>= 1) s2 += __shfl_xor(s2, off);
            if (lane == 0) s_invS[rr] = rsqrtf(s2 * (1.0f / D) + EPS);
        }
    }
    BLOCK_BARRIER();
    #pragma unroll
    for (int r = 0; r < PAD; ++r) {
        const float iv = s_invS[r];
        win[r][0] *= iv; win[r][1] *= iv; win[r][2] *= iv; win[r][3] *= iv;
    }
    BLOCK_BARRIER();   // protect s_invS reads before step-0 writes

    // ---- one step: consume `cur` (complete), other buffer in flight ----
    auto step = [&](float (&cur)[ST][4], int s) {
        #pragma unroll
        for (int r = 0; r < ST; ++r)
            s_part[r][tid] = cur[r][0]*cur[r][0] + cur[r][1]*cur[r][1]
                           + cur[r][2]*cur[r][2] + cur[r][3]*cur[r][3];
        BLOCK_BARRIER();
        {
            int rr = wave;
            float s1 = s_part[rr][lane]       + s_part[rr][lane + 64]
                     + s_part[rr][lane + 128] + s_part[rr][lane + 192];
            #pragma unroll
            for (int off = 32; off >= 1; off >>= 1) s1 += __shfl_xor(s1, off);
            if (lane == 0) s_invS[rr] = rsqrtf(s1 * (1.0f / D) + EPS);
            rr = wave + 4;
            float s2 = s_part[rr][lane]       + s_part[rr][lane + 64]
                     + s_part[rr][lane + 128] + s_part[rr][lane + 192];
            #pragma unroll
            for (int off = 32; off >= 1; off >>= 1) s2 += __shfl_xor(s2, off);
            if (lane == 0) s_invS[rr] = rsqrtf(s2 * (1.0f / D) + EPS);
        }
        BLOCK_BARRIER();

        const int base = l0 + s * ST;
        #pragma unroll
        for (int r = 0; r < ST; ++r) {
            const float iv = s_invS[r];
            cur[r][0] *= iv; cur[r][1] *= iv; cur[r][2] *= iv; cur[r][3] *= iv;
        }

        #pragma unroll
        for (int i = 0; i < ST; ++i) {
            float av[4];
            #pragma unroll
            for (int j = 0; j < 4; ++j) {
                float a = 0.0f;
                #pragma unroll
                for (int k = 0; k < 4; ++k) {
                    const int rel = i - 6 + 2 * k;
                    const float xv = (rel < 0) ? win[6 + rel][j] : cur[rel][j];
                    a = fmaf(wk[j][k], xv, a);
                }
                av[j] = a / (1.0f + __expf(-a));
            }
            f32x4 o = { av[0], av[1], av[2], av[3] };
            __builtin_nontemporal_store(o, (f32x4*)(ocol + (size_t)(base + i) * rs));
        }

        #pragma unroll
        for (int r = 0; r < PAD; ++r) {
            win[r][0] = cur[r + 2][0]; win[r][1] = cur[r + 2][1];
            win[r][2] = cur[r + 2][2]; win[r][3] = cur[r + 2][3];
        }

        if (s < NSTEP - 2) {
            #pragma unroll
            for (int r = 0; r < ST; ++r) {
                const float4 v = *(const float4*)(xcol + (size_t)(base + 2 * ST + r) * rs);
                cur[r][0] = v.x; cur[r][1] = v.y; cur[r][2] = v.z; cur[r][3] = v.w;
            }
        }
    };

    for (int s2 = 0; s2 < NSTEP; s2 += 2) {
        step(A, s2);
        step(Bv, s2 + 1);
    }
}

} // namespace

extern "C" void kernel_launch(void* const* d_in, const int* in_sizes, int n_in,
                              void* d_out, int out_size, void* d_ws, size_t ws_size,
                              hipStream_t stream) {
    const float* x  = (const float*)d_in[0];   // [B, L, HC, D] f32
    const float* nw = (const float*)d_in[1];   // [HC, D] f32
    const float* cw = (const float*)d_in[2];   // [C, 1, K] f32
    float* out = (float*)d_out;                // [B, L, HC, D] f32

    const int nblocks = B * HC * NT;           // 1024
    engram_shortconv_dbuf<<<dim3(nblocks), dim3(BDIM), 0, stream>>>(x, nw, cw, out);
}

// Round 7
// 111.747 us; speedup vs baseline: 1.2104x; 1.2104x over previous
//
#include <hip/hip_runtime.h>

namespace {

constexpr int B = 4, L = 4096, HC = 4, D = 1024, K = 4, DIL = 2;
constexpr int PAD = (K - 1) * DIL;   // 6
constexpr float EPS = 1e-5f;
constexpr int CL = 64;               // rows per block
constexpr int ST = 8;                // rows per step
constexpr int NSTEP = CL / ST;       // 8
constexpr int NT = L / CL;           // 64
constexpr int BDIM = 256;            // 4 waves

typedef float f32x4 __attribute__((ext_vector_type(4)));

// LDS-ordering barrier only: does NOT drain vmcnt, so staged loads stay in flight.
#define LGKM_BARRIER() do {                                    \
    asm volatile("s_waitcnt lgkmcnt(0)" ::: "memory");         \
    __builtin_amdgcn_s_barrier();                              \
} while (0)

__device__ __forceinline__ void stage16(const float* g, float* l) {
    __builtin_amdgcn_global_load_lds(
        (const __attribute__((address_space(1))) void*)g,
        (__attribute__((address_space(3))) void*)l, 16, 0, 0);
}

__global__ __launch_bounds__(BDIM, 2) void engram_shortconv_ldspipe(
    const float* __restrict__ x,
    const float* __restrict__ nw,
    const float* __restrict__ cw,
    float* __restrict__ out)
{
    __shared__ float s_buf[2][ST][BDIM * 4];   // 64 KiB staged x (dbuf)
    __shared__ float s_part[ST][BDIM];         // 8 KiB
    __shared__ float s_inv[ST];

    const int blk = blockIdx.x;
    const int t   = blk % NT;
    const int hc  = (blk / NT) % HC;
    const int b   = blk / (NT * HC);
    const int l0  = t * CL;

    const int tid  = threadIdx.x;
    const int wave = tid >> 6;
    const int lane = tid & 63;

    const size_t rs = (size_t)HC * D;
    const float* xcol = x   + ((size_t)b * L * HC + (size_t)hc) * D + tid * 4;
    float*       ocol = out + ((size_t)b * L * HC + (size_t)hc) * D + tid * 4;

    // ---- weights + halo register loads (issued before stages) ----
    const float4 nw4 = *(const float4*)(nw + (size_t)hc * D + tid * 4);
    float4 cwv[4];
    #pragma unroll
    for (int j = 0; j < 4; ++j)
        cwv[j] = *(const float4*)(cw + ((size_t)hc * D + tid * 4 + j) * K);

    float win[PAD][4];   // halo rows l0-6 .. l0-1
    if (l0 >= PAD) {
        #pragma unroll
        for (int r = 0; r < PAD; ++r) {
            const float4 v = *(const float4*)(xcol + (size_t)(l0 - PAD + r) * rs);
            win[r][0] = v.x; win[r][1] = v.y; win[r][2] = v.z; win[r][3] = v.w;
        }
    } else {
        #pragma unroll
        for (int r = 0; r < PAD; ++r) {
            const int l = l0 - PAD + r;
            float4 v = make_float4(0.f, 0.f, 0.f, 0.f);
            if (l >= 0) v = *(const float4*)(xcol + (size_t)l * rs);
            win[r][0] = v.x; win[r][1] = v.y; win[r][2] = v.z; win[r][3] = v.w;
        }
    }

    // ---- async stage of steps 0 and 1 (fly across the whole halo phase) ----
    #pragma unroll
    for (int r = 0; r < ST; ++r)
        stage16(xcol + (size_t)(l0 + r) * rs, &s_buf[0][r][wave * 256]);
    #pragma unroll
    for (int r = 0; r < ST; ++r)
        stage16(xcol + (size_t)(l0 + ST + r) * rs, &s_buf[1][r][wave * 256]);

    // ---- fold norm gain into conv taps ----
    float wk[4][4];
    {
        const float gv[4] = { nw4.x, nw4.y, nw4.z, nw4.w };
        #pragma unroll
        for (int j = 0; j < 4; ++j) {
            wk[j][0] = cwv[j].x * gv[j]; wk[j][1] = cwv[j].y * gv[j];
            wk[j][2] = cwv[j].z * gv[j]; wk[j][3] = cwv[j].w * gv[j];
        }
    }

    // ---- halo RMS (one-time, 2 lgkm-only barriers) ----
    #pragma unroll
    for (int r = 0; r < PAD; ++r)
        s_part[r][tid] = win[r][0]*win[r][0] + win[r][1]*win[r][1]
                       + win[r][2]*win[r][2] + win[r][3]*win[r][3];
    LGKM_BARRIER();
    {
        int rr = wave;
        float s1 = s_part[rr][lane]       + s_part[rr][lane + 64]
                 + s_part[rr][lane + 128] + s_part[rr][lane + 192];
        #pragma unroll
        for (int off = 32; off >= 1; off >>= 1) s1 += __shfl_xor(s1, off);
        if (lane == 0) s_inv[rr] = rsqrtf(s1 * (1.0f / D) + EPS);
        rr = wave + 4;
        if (rr < PAD) {
            float s2 = s_part[rr][lane]       + s_part[rr][lane + 64]
                     + s_part[rr][lane + 128] + s_part[rr][lane + 192];
            #pragma unroll
            for (int off = 32; off >= 1; off >>= 1) s2 += __shfl_xor(s2, off);
            if (lane == 0) s_inv[rr] = rsqrtf(s2 * (1.0f / D) + EPS);
        }
    }
    LGKM_BARRIER();
    #pragma unroll
    for (int r = 0; r < PAD; ++r) {
        const float iv = s_inv[r];
        win[r][0] *= iv; win[r][1] *= iv; win[r][2] *= iv; win[r][3] *= iv;
    }

    // ---- steady-state steps ----
    #pragma unroll
    for (int s = 0; s < NSTEP; ++s) {
        const int cb = s & 1;

        // Buffer cb ready when stage(s) retired. In-order vmcnt retirement:
        // newer-than-stage(s) op count = 8 (s=0), 16 (s=1), 24 (2<=s<=6), 16 (s=7).
        if (s == 0)                 asm volatile("s_waitcnt vmcnt(8)"  ::: "memory");
        else if (s == 1)            asm volatile("s_waitcnt vmcnt(16)" ::: "memory");
        else if (s == NSTEP - 1)    asm volatile("s_waitcnt vmcnt(16)" ::: "memory");
        else                        asm volatile("s_waitcnt vmcnt(24)" ::: "memory");
        __builtin_amdgcn_sched_barrier(0);

        // Each wave reads back exactly the bytes IT staged: no barrier needed.
        float cur[ST][4];
        #pragma unroll
        for (int r = 0; r < ST; ++r) {
            const f32x4 v = *(const f32x4*)&s_buf[cb][r][tid * 4];
            cur[r][0] = v.x; cur[r][1] = v.y; cur[r][2] = v.z; cur[r][3] = v.w;
        }
        #pragma unroll
        for (int r = 0; r < ST; ++r)
            s_part[r][tid] = cur[r][0]*cur[r][0] + cur[r][1]*cur[r][1]
                           + cur[r][2]*cur[r][2] + cur[r][3]*cur[r][3];

        // Re-stage this buffer with step s+2 (ds_reads above are complete:
        // squares consumed them; explicit lgkm wait makes it airtight).
        if (s < NSTEP - 2) {
            asm volatile("s_waitcnt lgkmcnt(0)" ::: "memory");
            __builtin_amdgcn_sched_barrier(0);
            #pragma unroll
            for (int r = 0; r < ST; ++r)
                stage16(xcol + (size_t)(l0 + (s + 2) * ST + r) * rs,
                        &s_buf[cb][r][wave * 256]);
            __builtin_amdgcn_sched_barrier(0);
        }

        LGKM_BARRIER();
        {
            int rr = wave;
            float s1 = s_part[rr][lane]       + s_part[rr][lane + 64]
                     + s_part[rr][lane + 128] + s_part[rr][lane + 192];
            #pragma unroll
            for (int off = 32; off >= 1; off >>= 1) s1 += __shfl_xor(s1, off);
            if (lane == 0) s_inv[rr] = rsqrtf(s1 * (1.0f / D) + EPS);
            rr = wave + 4;
            float s2 = s_part[rr][lane]       + s_part[rr][lane + 64]
                     + s_part[rr][lane + 128] + s_part[rr][lane + 192];
            #pragma unroll
            for (int off = 32; off >= 1; off >>= 1) s2 += __shfl_xor(s2, off);
            if (lane == 0) s_inv[rr] = rsqrtf(s2 * (1.0f / D) + EPS);
        }
        LGKM_BARRIER();

        const int base = l0 + s * ST;
        #pragma unroll
        for (int r = 0; r < ST; ++r) {
            const float iv = s_inv[r];
            cur[r][0] *= iv; cur[r][1] *= iv; cur[r][2] *= iv; cur[r][3] *= iv;
        }

        #pragma unroll
        for (int i = 0; i < ST; ++i) {
            float av[4];
            #pragma unroll
            for (int j = 0; j < 4; ++j) {
                float a = 0.0f;
                #pragma unroll
                for (int k = 0; k < 4; ++k) {
                    const int rel = i - 6 + 2 * k;
                    const float xv = (rel < 0) ? win[6 + rel][j] : cur[rel][j];
                    a = fmaf(wk[j][k], xv, a);
                }
                av[j] = a / (1.0f + __expf(-a));
            }
            f32x4 o = { av[0], av[1], av[2], av[3] };
            *(f32x4*)(ocol + (size_t)(base + i) * rs) = o;
        }

        // rotate halo (scaled rows base+2 .. base+7)
        #pragma unroll
        for (int r = 0; r < PAD; ++r) {
            win[r][0] = cur[r + 2][0]; win[r][1] = cur[r + 2][1];
            win[r][2] = cur[r + 2][2]; win[r][3] = cur[r + 2][3];
        }
    }
}

} // namespace

extern "C" void kernel_launch(void* const* d_in, const int* in_sizes, int n_in,
                              void* d_out, int out_size, void* d_ws, size_t ws_size,
                              hipStream_t stream) {
    const float* x  = (const float*)d_in[0];   // [B, L, HC, D] f32
    const float* nw = (const float*)d_in[1];   // [HC, D] f32
    const float* cw = (const float*)d_in[2];   // [C, 1, K] f32
    float* out = (float*)d_out;                // [B, L, HC, D] f32

    const int nblocks = B * HC * NT;           // 1024
    engram_shortconv_ldspipe<<<dim3(nblocks), dim3(BDIM), 0, stream>>>(x, nw, cw, out);
}